// Round 4
// baseline (298.286 us; speedup 1.0000x reference)
//
#include <hip/hip_runtime.h>
#include <math.h>

// GroupedQueryAttention: B=4,S=128,D=4096,H=32,KV=8,HD=128,REP=4
// Round 10:
//  - transpose_tile: stores now lane-contiguous per instruction (was 16B @
//    64B stride = 4x L2 transactions; prep ran at 2.3 TB/s, 3.5% VALU).
//    LDS tile XOR-swizzled by (r>>3)&7 to keep column reads 2-way (free).
//  - wo-transpose packed into the prep launch (independent of QKV gemm);
//    attention launch is now pure attn.
//  - gemm tiles 32m x 128n: QKV grid 768, O grid 512 (was 384/256 = 1.5/1
//    blocks/CU -> latency-bound at 1 wave/SIMD). Depth-2 counted vmcnt(5).

#define B_   4
#define S_   128
#define D_   4096
#define H_   32
#define KV_  8
#define HD_  128
#define M_   (B_ * S_)        // 512 rows
#define NQKV 6144
#define SCALE_ 0.088388347648318447f  // 1/sqrt(128)

typedef _Float16 half_t;
typedef half_t f16x8 __attribute__((ext_vector_type(8)));
typedef float  f32x4 __attribute__((ext_vector_type(4)));

__device__ inline void load_lds16(const void* g, void* l) {
    __builtin_amdgcn_global_load_lds((const __attribute__((address_space(1))) void*)g,
                                     (__attribute__((address_space(3))) void*)l,
                                     16, 0, 0);
}

// ---------------------------------------------------------------------------
// One 128n x 64k transpose tile: W[k0..+64][nsrc0..+128] fp32 ->
// Wt slab (k0/64): rows ndst0..+128 x 64 halfs (16KB contiguous write).
// 256 threads. Stores are lane-contiguous per instruction (1KB/wave-instr);
// LDS float4-column swizzle ^(r>>3)&7 keeps the column reads 2-way.
__device__ void transpose_tile(const float* __restrict__ src, int Nsrc, int nsrc0,
                               int ndst0, int k0, int Ntot,
                               half_t* __restrict__ Wt, void* ldsraw) {
    float (*tile)[132] = (float(*)[132])ldsraw;   // [64k][128n], pad 132
    const int t = threadIdx.x;
#pragma unroll
    for (int p = 0; p < 8; ++p) {
        int idx = t + p * 256;              // 2048 float4 tasks
        int r = idx >> 5, c4 = idx & 31;    // 64 k-rows x 32 float4
        *(float4*)&tile[r][((c4 ^ ((r >> 3) & 7)) * 4)] =
            *(const float4*)&src[(size_t)(k0 + r) * Nsrc + nsrc0 + c4 * 4];
    }
    __syncthreads();
    // lane t, pass u: 16B store at tile_base + u*4096 + t*16 (contiguous).
    // That chunk holds n = u*32+(t>>3), k_local = kh*32 + cc*8 + i (i=0..7),
    // kh=(t>>2)&1, cc=t&3.
    const int kh = (t >> 2) & 1, cc = t & 3, dd = t >> 3;
    const int rbase = kh * 32 + cc * 8;
    const int h3 = 4 * kh + cc;             // = (r>>3)&7 for these rows
    size_t tb = ((size_t)(k0 >> 6) * Ntot + ndst0) * 64;   // halfs
#pragma unroll
    for (int u = 0; u < 4; ++u) {
        int n = u * 32 + dd;
        int pc = ((n >> 2) ^ h3) * 4 + (n & 3);
        __align__(16) half_t hs[8];
#pragma unroll
        for (int i = 0; i < 8; ++i)
            hs[i] = (half_t)tile[rbase + i][pc];
        *(uint4*)&Wt[tb + (size_t)u * 2048 + t * 8] = *(uint4*)hs;
    }
}

// ---------------------------------------------------------------------------
// Packed prep: QKV weight transpose (3072) + x fp32->fp16 (512) +
// wo transpose (2048). 5632 blocks, all memory-bound.
__global__ __launch_bounds__(256)
void prep_all(const float* __restrict__ wq, const float* __restrict__ wk,
              const float* __restrict__ wv, const float* __restrict__ wo,
              const float* __restrict__ x,
              half_t* __restrict__ Wt, half_t* __restrict__ WtO,
              half_t* __restrict__ x16) {
    __shared__ __align__(16) char lds[33792];
    const int bx = blockIdx.x;
    if (bx < 3072) {
        int nt = bx % 48, kt = bx / 48;
        const float* src; int Nsrc, ns0, nd0;
        if (nt < 32)      { src = wq; Nsrc = 4096; ns0 = nt * 128;        nd0 = nt * 128; }
        else if (nt < 40) { src = wk; Nsrc = 1024; ns0 = (nt - 32) * 128; nd0 = 4096 + (nt - 32) * 128; }
        else              { src = wv; Nsrc = 1024; ns0 = (nt - 40) * 128; nd0 = 5120 + (nt - 40) * 128; }
        transpose_tile(src, Nsrc, ns0, nd0, kt * 64, NQKV, Wt, lds);
    } else if (bx < 3584) {
        int i0 = (bx - 3072) * 1024 + threadIdx.x;
#pragma unroll
        for (int j = 0; j < 4; ++j) {
            int i = i0 + j * 256;
            float4 f = ((const float4*)x)[i];
            __align__(8) half_t h4[4] = {(half_t)f.x, (half_t)f.y, (half_t)f.z, (half_t)f.w};
            ((uint2*)x16)[i] = *(uint2*)h4;
        }
    } else {
        int tw = bx - 3584;                  // 2048 = 32 n-tiles x 64 k-tiles
        transpose_tile(wo, 4096, (tw & 31) * 128, (tw & 31) * 128,
                       (tw >> 5) * 64, 4096, WtO, lds);
    }
}

// ---------------------------------------------------------------------------
// 32m x 128n full-K=4096 gemm core, 256 threads (4 waves, each 32m x 32n).
// 3 LDS buffers, depth-2 DMA prefetch, counted vmcnt(5) + raw s_barrier.
__device__ __forceinline__ void stage32x128(const half_t* __restrict__ A,
                                            const half_t* __restrict__ Bbase,
                                            int N, int m0, int n0, int kc,
                                            half_t* AsD, half_t* BsD, int tid) {
    const int lane = tid & 63, tB = tid & 192;
    const half_t* Bslab = Bbase + ((size_t)(kc >> 6) * N + n0) * 64;
    {                                        // A: 256 tasks (32 rows x 8 chunks)
        int task = tB + lane;
        int r = task >> 3, os = (task ^ r) & 7;
        load_lds16(&A[(size_t)(m0 + r) * 4096 + kc + os * 8], AsD + tB * 8);
    }
#pragma unroll
    for (int p = 0; p < 4; ++p) {            // B: 1024 tasks (128 rows x 8 chunks)
        int tb = p * 256 + tB;
        int task = tb + lane;
        int r = task >> 3, os = (task ^ r) & 7;
        load_lds16(&Bslab[(size_t)r * 64 + os * 8], BsD + tb * 8);
    }
}

__device__ __forceinline__ void compute32x128(const half_t* AsD, const half_t* BsD,
                                              int tid, f32x4 (&acc)[2][2]) {
    const int lane = tid & 63;
    const int quad = lane >> 4, l16 = lane & 15;
    const int wn = (tid >> 6) * 32;
    half_t (*As)[64] = (half_t(*)[64])AsD;
    half_t (*Bs)[64] = (half_t(*)[64])BsD;
#pragma unroll
    for (int kk = 0; kk < 2; ++kk) {
        f16x8 af[2], bf[2];
        int L = kk * 4 + quad;
#pragma unroll
        for (int i = 0; i < 2; ++i) {
            int ra = i * 16 + l16;
            af[i] = *(const f16x8*)&As[ra][(L ^ (ra & 7)) * 8];
        }
#pragma unroll
        for (int j = 0; j < 2; ++j) {
            int rb = wn + j * 16 + l16;
            bf[j] = *(const f16x8*)&Bs[rb][(L ^ (rb & 7)) * 8];
        }
#pragma unroll
        for (int i = 0; i < 2; ++i)
#pragma unroll
            for (int j = 0; j < 2; ++j)
                acc[i][j] = __builtin_amdgcn_mfma_f32_16x16x32_f16(af[i], bf[j], acc[i][j], 0, 0, 0);
    }
}

__device__ __forceinline__ void fence_step(int n) {
    // wait until only n VMEM ops outstanding, then barrier WITHOUT draining
    if (n == 5)      asm volatile("s_waitcnt vmcnt(5)" ::: "memory");
    else if (n == 0) asm volatile("s_waitcnt vmcnt(0)" ::: "memory");
    __builtin_amdgcn_s_barrier();
    __builtin_amdgcn_sched_barrier(0);
}

__device__ __forceinline__ void gemm32x128(const half_t* __restrict__ A,
                                           const half_t* __restrict__ Bbase,
                                           int N, int m0, int n0, char* lds,
                                           f32x4 (&acc)[2][2]) {
    const int tid = threadIdx.x;
    half_t* As0 = (half_t*)lds;              // [3][32][64]   12KB
    half_t* Bs0 = (half_t*)(lds + 12288);    // [3][128][64]  48KB
    stage32x128(A, Bbase, N, m0, n0, 0,  As0,        Bs0,        tid);
    stage32x128(A, Bbase, N, m0, n0, 64, As0 + 2048, Bs0 + 8192, tid);
    fence_step(5);                           // tile 0 landed; tile 1 in flight
    int cur = 0, pf = 2;
    for (int it = 0; it < 62; ++it) {
        stage32x128(A, Bbase, N, m0, n0, (it + 2) * 64,
                    As0 + pf * 2048, Bs0 + pf * 8192, tid);
        compute32x128(As0 + cur * 2048, Bs0 + cur * 8192, tid, acc);
        fence_step(5);                       // tile it+1 landed; it+2 in flight
        cur = (cur == 2) ? 0 : cur + 1;
        pf  = (pf  == 2) ? 0 : pf  + 1;
    }
    compute32x128(As0 + cur * 2048, Bs0 + cur * 8192, tid, acc);  // tile 62
    fence_step(0);                           // tile 63 landed
    cur = (cur == 2) ? 0 : cur + 1;
    compute32x128(As0 + cur * 2048, Bs0 + cur * 8192, tid, acc);  // tile 63
    __syncthreads();                         // LDS free for epilogue reuse
}

// ---------------------------------------------------------------------------
// QKV gemm + fused bias+RoPE+fp16 epilogue.
// Grid 768 = 16 m-tiles x 48 n-tiles, XCD-swizzled (same-n blocks same XCD).
__global__ __launch_bounds__(256, 2)
void gemm_qkv_fused(const half_t* __restrict__ x16, const half_t* __restrict__ Wt,
                    const float* __restrict__ bq, const float* __restrict__ bk,
                    const float* __restrict__ bv, const float* __restrict__ fc,
                    const float* __restrict__ fs, half_t* __restrict__ q16,
                    half_t* __restrict__ k16, half_t* __restrict__ vt16) {
    __shared__ __align__(16) char lds[61440];
    const int bx = blockIdx.x;
    const int o = (bx & 7) * 96 + (bx >> 3);  // bijective, 768 = 8 XCD x 96
    const int nb = o >> 4, mb = o & 15;
    const int m0 = mb * 32, n0 = nb * 128;

    f32x4 acc[2][2] = {};
    gemm32x128(x16, Wt, NQKV, m0, n0, lds, acc);

    const int tid = threadIdx.x;
    const int lane = tid & 63;
    const int quad = lane >> 4, l16 = lane & 15;
    const int wn = (tid >> 6) * 32;

    if (n0 < 5120) {
        // Q or K tile: bias + RoPE (adjacent-lane pairs) + fp16 store
        const bool isQ = n0 < 4096;
        const float* bias = isQ ? bq : bk;
        const int bOff = isQ ? 0 : 4096;
        half_t* dst = isQ ? q16 : k16;
        const int ldd = isQ ? 4096 : 1024;
#pragma unroll
        for (int i = 0; i < 2; ++i)
#pragma unroll
            for (int j = 0; j < 2; ++j) {
                const int col = n0 + wn + j * 16 + l16;   // even iff l16 even
                const int d2 = (col >> 1) & 63;
                const float bcol = bias[col - bOff];
#pragma unroll
                for (int rg = 0; rg < 4; ++rg) {
                    const int row = m0 + i * 16 + quad * 4 + rg;
                    float v = acc[i][j][rg] + bcol;
                    float p = __shfl_xor(v, 1);           // (re,im) partner
                    const int iloc = row & 127;
                    const float c = fc[iloc * 64 + d2], sn = fs[iloc * 64 + d2];
                    float ov = (l16 & 1) ? (p * sn + v * c)   // im' = re*s + im*c
                                         : (v * c - p * sn);  // re' = re*c - im*s
                    float o2 = __shfl_xor(ov, 1);
                    if (!(l16 & 1)) {
                        __align__(4) half_t hh[2] = {(half_t)ov, (half_t)o2};
                        *(unsigned int*)&dst[(size_t)row * ldd + (col - bOff)] =
                            *(unsigned int*)hh;
                    }
                }
            }
    } else {
        // V tile: bias -> LDS fp16 -> transposed coalesced store to vt16[d][i]
        half_t (*Th)[136] = (half_t(*)[136])lds;   // 32 x 136 x 2 = 8704 B
#pragma unroll
        for (int i = 0; i < 2; ++i)
#pragma unroll
            for (int j = 0; j < 2; ++j) {
                const int cl = wn + j * 16 + l16;
                const float bcol = bv[n0 - 5120 + cl];
#pragma unroll
                for (int rg = 0; rg < 4; ++rg)
                    Th[i * 16 + quad * 4 + rg][cl] = (half_t)(acc[i][j][rg] + bcol);
            }
        __syncthreads();
        const int d = tid >> 1, ih = tid & 1;     // 128 d x 2 i-halves of 16
        const int kv = (n0 - 5120) >> 7;
        const int b = mb >> 2, i0 = (mb & 3) * 32;
        __align__(16) half_t hs[16];
#pragma unroll
        for (int u = 0; u < 16; ++u) hs[u] = Th[ih * 16 + u][d];
        size_t base = ((size_t)(b * 8 + kv) * 128 + d) * 128 + i0 + ih * 16;
#pragma unroll
        for (int u = 0; u < 2; ++u)
            *(uint4*)&vt16[base + u * 8] = *(uint4*)&hs[u * 8];
    }
}

// ---------------------------------------------------------------------------
// Fused attention: one block per (b, h, 32-row q-chunk). Grid 512.
__global__ __launch_bounds__(256, 2)
void fused_attn(const half_t* __restrict__ q16, const half_t* __restrict__ k16,
                const half_t* __restrict__ vt16, half_t* __restrict__ a16) {
    __shared__ __align__(16) char lds[62464];
    half_t (*Qs)[136] = (half_t(*)[136])lds;            //  8704 B
    half_t (*Ks)[136] = (half_t(*)[136])(lds + 8704);   // 34816 B
    float (*Ps)[132]  = (float(*)[132])(lds + 43520);   // 16896 B
    float (*red)[16]  = (float(*)[16])(lds + 60416);    //  2048 B

    const int tid = threadIdx.x;
    const int qi = blockIdx.x & 3, h = (blockIdx.x >> 2) & 31, b = blockIdx.x >> 7;
    const int kv = h >> 2;
    const int qbase = qi * 32;
    const int lane = tid & 63, w = tid >> 6;
    const int quad = lane >> 4, l16 = lane & 15;
    const int m0 = (w & 1) * 16, half64 = (w >> 1) * 64;

#pragma unroll
    for (int p = 0; p < 2; ++p) {
        int task = tid + p * 256;
        int r = task >> 4, c = task & 15;
        *(uint4*)&Qs[r][c * 8] =
            *(const uint4*)&q16[((size_t)(b * 128 + qbase + r) * 32 + h) * 128 + c * 8];
    }
#pragma unroll
    for (int p = 0; p < 8; ++p) {
        int task = tid + p * 256;
        int r = task >> 4, c = task & 15;
        *(uint4*)&Ks[r][c * 8] =
            *(const uint4*)&k16[((size_t)(b * 128 + r) * 8 + kv) * 128 + c * 8];
    }
    __syncthreads();

    // phase 1: S = Q K^T
    f32x4 s[4] = {};
#pragma unroll
    for (int kc = 0; kc < 4; ++kc) {
        f16x8 af = *(const f16x8*)&Qs[m0 + l16][kc * 32 + quad * 8];
#pragma unroll
        for (int jb = 0; jb < 4; ++jb) {
            f16x8 bf = *(const f16x8*)&Ks[half64 + jb * 16 + l16][kc * 32 + quad * 8];
            s[jb] = __builtin_amdgcn_mfma_f32_16x16x32_f16(af, bf, s[jb], 0, 0, 0);
        }
    }
#pragma unroll
    for (int jb = 0; jb < 4; ++jb) {
        int j = half64 + jb * 16 + l16;
#pragma unroll
        for (int rg = 0; rg < 4; ++rg) {
            int row = m0 + quad * 4 + rg;
            Ps[row][j] = (j <= qbase + row) ? s[jb][rg] * SCALE_ : -1e30f;
        }
    }
    __syncthreads();

    // softmax: thread t -> row r, 16-col segment seg
    const int r = tid >> 3, seg = tid & 7;
    float mx = -1e30f;
#pragma unroll
    for (int i = 0; i < 16; ++i) mx = fmaxf(mx, Ps[r][seg * 16 + i]);
    red[r][seg] = mx;
    __syncthreads();

    uint4 vstage[8];
#pragma unroll
    for (int p = 0; p < 8; ++p) {
        int task = tid + p * 256;
        int rr = task >> 4, c = task & 15;
        vstage[p] = *(const uint4*)&vt16[((size_t)(b * 8 + kv) * 128 + rr) * 128 + c * 8];
    }
    float m = red[r][0];
#pragma unroll
    for (int i = 1; i < 8; ++i) m = fmaxf(m, red[r][i]);
    float sum = 0.f;
#pragma unroll
    for (int i = 0; i < 16; ++i) {
        float e = __expf(Ps[r][seg * 16 + i] - m);
        Ps[r][seg * 16 + i] = e;
        sum += e;
    }
    red[r][8 + seg] = sum;
#pragma unroll
    for (int p = 0; p < 8; ++p) {
        int task = tid + p * 256;
        int rr = task >> 4, c = task & 15;
        *(uint4*)&Ks[rr][c * 8] = vstage[p];   // Vt[d][j]
    }
    __syncthreads();

    float tot = 0.f;
#pragma unroll
    for (int i = 0; i < 8; ++i) tot += red[r][8 + i];
    float inv = 1.0f / tot;
#pragma unroll
    for (int i = 0; i < 16; ++i)
        Qs[r][seg * 16 + i] = (half_t)(Ps[r][seg * 16 + i] * inv);
    __syncthreads();

    // phase 2: O = P V
    f32x4 o[4] = {};
#pragma unroll
    for (int jc = 0; jc < 4; ++jc) {
        f16x8 af = *(const f16x8*)&Qs[m0 + l16][jc * 32 + quad * 8];
#pragma unroll
        for (int db = 0; db < 4; ++db) {
            f16x8 bf = *(const f16x8*)&Ks[half64 + db * 16 + l16][jc * 32 + quad * 8];
            o[db] = __builtin_amdgcn_mfma_f32_16x16x32_f16(af, bf, o[db], 0, 0, 0);
        }
    }
#pragma unroll
    for (int db = 0; db < 4; ++db) {
        int d = half64 + db * 16 + l16;
#pragma unroll
        for (int rg = 0; rg < 4; ++rg) {
            int row = m0 + quad * 4 + rg;
            a16[(size_t)(b * 128 + qbase + row) * 4096 + h * 128 + d] = (half_t)o[db][rg];
        }
    }
}

// ---------------------------------------------------------------------------
// O projection + fused +bo, fp32 store. Grid 512 = 16 m x 32 n, XCD-swizzled.
__global__ __launch_bounds__(256, 2)
void gemm_o_fused(const half_t* __restrict__ a16, const half_t* __restrict__ WtO,
                  const float* __restrict__ bo, float* __restrict__ out) {
    __shared__ __align__(16) char lds[61440];
    const int bx = blockIdx.x;
    const int o = (bx & 7) * 64 + (bx >> 3);  // bijective, 512 = 8 XCD x 64
    const int nb = o >> 4, mb = o & 15;
    const int m0 = mb * 32, n0 = nb * 128;

    f32x4 acc[2][2] = {};
    gemm32x128(a16, WtO, 4096, m0, n0, lds, acc);

    const int tid = threadIdx.x;
    const int lane = tid & 63;
    const int quad = lane >> 4, l16 = lane & 15;
    const int wn = (tid >> 6) * 32;
#pragma unroll
    for (int i = 0; i < 2; ++i)
#pragma unroll
        for (int j = 0; j < 2; ++j) {
            const int col = n0 + wn + j * 16 + l16;
            const float bcol = bo[col];
#pragma unroll
            for (int rg = 0; rg < 4; ++rg) {
                const int row = m0 + i * 16 + quad * 4 + rg;
                out[(size_t)row * 4096 + col] = acc[i][j][rg] + bcol;
            }
        }
}

// ---------------------------------------------------------------------------
extern "C" void kernel_launch(void* const* d_in, const int* in_sizes, int n_in,
                              void* d_out, int out_size, void* d_ws, size_t ws_size,
                              hipStream_t stream) {
    const float* x    = (const float*)d_in[0];
    const float* fc   = (const float*)d_in[2];
    const float* fs   = (const float*)d_in[3];
    const float* wq   = (const float*)d_in[7];
    const float* bq   = (const float*)d_in[8];
    const float* wk   = (const float*)d_in[9];
    const float* bk   = (const float*)d_in[10];
    const float* wv   = (const float*)d_in[11];
    const float* bv   = (const float*)d_in[12];
    const float* wo   = (const float*)d_in[13];
    const float* bo   = (const float*)d_in[14];
    float* out = (float*)d_out;

    half_t* x16  = (half_t*)d_ws;            //  2,097,152 h
    half_t* a16  = x16 + 2097152;            //  2,097,152 h
    half_t* q16  = a16 + 2097152;            //  2,097,152 h
    half_t* k16  = q16 + 2097152;            //    524,288 h
    half_t* vt16 = k16 + 524288;             //    524,288 h
    half_t* Wt   = vt16 + 524288;            // 25,165,824 h (ends @65,011,712 B)
    half_t* WtO  = Wt + 25165824;            // 16,777,216 h (32 MB, ends @98.5 MB)

    // 1. all transposes (wq/wk/wv + wo) + x convert, one memory-bound launch
    prep_all<<<5632, 256, 0, stream>>>(wq, wk, wv, wo, x, Wt, WtO, x16);

    // 2. QKV gemm, full-K, depth-2 counted-vmcnt pipeline, fused epilogue
    gemm_qkv_fused<<<768, 256, 0, stream>>>(x16, Wt, bq, bk, bv, fc, fs,
                                            q16, k16, vt16);

    // 3. fused attention
    fused_attn<<<512, 256, 0, stream>>>(q16, k16, vt16, a16);

    // 4. O projection, full-K, depth-2 counted-vmcnt pipeline, fused +bo
    gemm_o_fused<<<512, 256, 0, stream>>>(a16, WtO, bo, out);
}

// Round 5
// 295.175 us; speedup vs baseline: 1.0105x; 1.0105x over previous
//
#include <hip/hip_runtime.h>
#include <math.h>

// GroupedQueryAttention: B=4,S=128,D=4096,H=32,KV=8,HD=128,REP=4
// Round 11: r0's fat-wave split-K structure + the pipeline fixes proven in
// r9/r10, minus the regressions:
//  - gemm: 128x128 tiles, acc[4][4]/wave (32 MFMA per 2 steps), z=4 HBM
//    split-K (grid 768/512 = 3 blocks/CU at 48KB LDS)
//  - BK=32: 64B LDS rows are inherently bank-conflict-free for the
//    ds_read_b128 fragment reads (4 quads cover the full row) - no swizzle
//  - triple-buffer depth-2 prefetch, counted s_waitcnt vmcnt(4) + raw
//    s_barrier (never drain in the main loop)
//  - wo-transpose packed into the QKV gemm launch (hidden under compute,
//    r0-proven); prep is x16 + wq/wk/wv-T only
//  - reduce/rope + o_reduce HBM-partial kernels (r0-proven)

#define B_   4
#define S_   128
#define D_   4096
#define H_   32
#define KV_  8
#define HD_  128
#define M_   (B_ * S_)        // 512 rows
#define NQKV 6144
#define SCALE_ 0.088388347648318447f  // 1/sqrt(128)

typedef _Float16 half_t;
typedef half_t f16x8 __attribute__((ext_vector_type(8)));
typedef float  f32x4 __attribute__((ext_vector_type(4)));

__device__ inline void load_lds16(const void* g, void* l) {
    __builtin_amdgcn_global_load_lds((const __attribute__((address_space(1))) void*)g,
                                     (__attribute__((address_space(3))) void*)l,
                                     16, 0, 0);
}

// ---------------------------------------------------------------------------
// One 128n x 64k transpose tile: W[k0..+64][nsrc0..+128] fp32 ->
// Wt slab (k0/64): rows ndst0..+128 x 64 halfs (16KB contiguous write).
// 256 threads. Lane-contiguous stores, swizzled LDS tile (0 conflicts, r10).
__device__ void transpose_tile(const float* __restrict__ src, int Nsrc, int nsrc0,
                               int ndst0, int k0, int Ntot,
                               half_t* __restrict__ Wt, void* ldsraw) {
    float (*tile)[132] = (float(*)[132])ldsraw;   // [64k][128n], pad 132
    const int t = threadIdx.x;
#pragma unroll
    for (int p = 0; p < 8; ++p) {
        int idx = t + p * 256;              // 2048 float4 tasks
        int r = idx >> 5, c4 = idx & 31;    // 64 k-rows x 32 float4
        *(float4*)&tile[r][((c4 ^ ((r >> 3) & 7)) * 4)] =
            *(const float4*)&src[(size_t)(k0 + r) * Nsrc + nsrc0 + c4 * 4];
    }
    __syncthreads();
    const int kh = (t >> 2) & 1, cc = t & 3, dd = t >> 3;
    const int rbase = kh * 32 + cc * 8;
    const int h3 = 4 * kh + cc;             // = (r>>3)&7 for these rows
    size_t tb = ((size_t)(k0 >> 6) * Ntot + ndst0) * 64;   // halfs
#pragma unroll
    for (int u = 0; u < 4; ++u) {
        int n = u * 32 + dd;
        int pc = ((n >> 2) ^ h3) * 4 + (n & 3);
        __align__(16) half_t hs[8];
#pragma unroll
        for (int i = 0; i < 8; ++i)
            hs[i] = (half_t)tile[rbase + i][pc];
        *(uint4*)&Wt[tb + (size_t)u * 2048 + t * 8] = *(uint4*)hs;
    }
}

// ---------------------------------------------------------------------------
// Packed prep: QKV weight transpose (3072) + x fp32->fp16 (512).
__global__ __launch_bounds__(256)
void prep_qkv(const float* __restrict__ wq, const float* __restrict__ wk,
              const float* __restrict__ wv, const float* __restrict__ x,
              half_t* __restrict__ Wt, half_t* __restrict__ x16) {
    __shared__ __align__(16) char lds[33792];
    const int bx = blockIdx.x;
    if (bx < 3072) {
        int nt = bx % 48, kt = bx / 48;
        const float* src; int Nsrc, ns0, nd0;
        if (nt < 32)      { src = wq; Nsrc = 4096; ns0 = nt * 128;        nd0 = nt * 128; }
        else if (nt < 40) { src = wk; Nsrc = 1024; ns0 = (nt - 32) * 128; nd0 = 4096 + (nt - 32) * 128; }
        else              { src = wv; Nsrc = 1024; ns0 = (nt - 40) * 128; nd0 = 5120 + (nt - 40) * 128; }
        transpose_tile(src, Nsrc, ns0, nd0, kt * 64, NQKV, Wt, lds);
    } else {
        int i0 = (bx - 3072) * 1024 + threadIdx.x;
#pragma unroll
        for (int j = 0; j < 4; ++j) {
            int i = i0 + j * 256;
            float4 f = ((const float4*)x)[i];
            __align__(8) half_t h4[4] = {(half_t)f.x, (half_t)f.y, (half_t)f.z, (half_t)f.w};
            ((uint2*)x16)[i] = *(uint2*)h4;
        }
    }
}

// ---------------------------------------------------------------------------
// 128x128 gemm core, BK=32, 256 threads (4 waves, each 64x64, acc[4][4]).
// 3 LDS buffers (A 8KB + B 8KB each = 48KB total), depth-2 DMA prefetch,
// counted vmcnt(4) + raw s_barrier. 64B LDS rows -> conflict-free b128 reads.
__device__ __forceinline__ void stage_bk32(const half_t* __restrict__ A,
                                           const half_t* __restrict__ Bbase,
                                           int N, int m0, int n0, int kc,
                                           half_t* AsD, half_t* BsD, int tid) {
    const int lane = tid & 63, tB = tid & 192;
    const half_t* Bslab = Bbase + ((size_t)(kc >> 6) * N + n0) * 64 + ((kc >> 5) & 1) * 32;
#pragma unroll
    for (int p = 0; p < 2; ++p) {
        int tb = p * 256 + tB;              // wave-uniform LDS base
        int task = tb + lane;
        int r = task >> 2, c = task & 3;    // 128 rows x 4 16B-chunks
        load_lds16(&A[(size_t)(m0 + r) * 4096 + kc + c * 8], AsD + tb * 8);
        load_lds16(&Bslab[(size_t)r * 64 + c * 8],           BsD + tb * 8);
    }
}

__device__ __forceinline__ void compute_bk32(const half_t* AsD, const half_t* BsD,
                                             int tid, f32x4 (&acc)[4][4]) {
    const int lane = tid & 63;
    const int quad = lane >> 4, l16 = lane & 15;
    const int w = tid >> 6;
    const int wm = (w & 1) * 64, wn = (w >> 1) * 64;
    half_t (*As)[32] = (half_t(*)[32])AsD;
    half_t (*Bs)[32] = (half_t(*)[32])BsD;
    f16x8 af[4], bf[4];
#pragma unroll
    for (int i = 0; i < 4; ++i)
        af[i] = *(const f16x8*)&As[wm + i * 16 + l16][quad * 8];
#pragma unroll
    for (int j = 0; j < 4; ++j)
        bf[j] = *(const f16x8*)&Bs[wn + j * 16 + l16][quad * 8];
#pragma unroll
    for (int i = 0; i < 4; ++i)
#pragma unroll
        for (int j = 0; j < 4; ++j)
            acc[i][j] = __builtin_amdgcn_mfma_f32_16x16x32_f16(af[i], bf[j], acc[i][j], 0, 0, 0);
}

__device__ __forceinline__ void fence4() {
    asm volatile("s_waitcnt vmcnt(4)" ::: "memory");
    __builtin_amdgcn_s_barrier();
    __builtin_amdgcn_sched_barrier(0);
}
__device__ __forceinline__ void fence0() {
    asm volatile("s_waitcnt vmcnt(0)" ::: "memory");
    __builtin_amdgcn_s_barrier();
    __builtin_amdgcn_sched_barrier(0);
}

__device__ __forceinline__ void gemm128_bk32(const half_t* __restrict__ A,
                                             const half_t* __restrict__ Bbase,
                                             int N, int m0, int n0, int kbase,
                                             int ksteps, char* lds,
                                             f32x4 (&acc)[4][4]) {
    const int tid = threadIdx.x;
    half_t* As0 = (half_t*)lds;              // [3][128][32] halfs, 8KB each
    half_t* Bs0 = (half_t*)(lds + 24576);    // [3][128][32]
    stage_bk32(A, Bbase, N, m0, n0, kbase,      As0,        Bs0,        tid);
    stage_bk32(A, Bbase, N, m0, n0, kbase + 32, As0 + 4096, Bs0 + 4096, tid);
    fence4();                                // tile0 landed; tile1 in flight
    int cur = 0, pf = 2;
    for (int it = 0; it < ksteps - 2; ++it) {
        stage_bk32(A, Bbase, N, m0, n0, kbase + (it + 2) * 32,
                   As0 + pf * 4096, Bs0 + pf * 4096, tid);
        compute_bk32(As0 + cur * 4096, Bs0 + cur * 4096, tid, acc);
        fence4();                            // tile it+1 landed; it+2 in flight
        cur = (cur == 2) ? 0 : cur + 1;
        pf  = (pf  == 2) ? 0 : pf  + 1;
    }
    compute_bk32(As0 + cur * 4096, Bs0 + cur * 4096, tid, acc);
    fence0();                                // last tile landed
    cur = (cur == 2) ? 0 : cur + 1;
    compute_bk32(As0 + cur * 4096, Bs0 + cur * 4096, tid, acc);
}

// ---------------------------------------------------------------------------
// Packed: QKV gemm (192*z blocks, z=4 split-K) + wo transpose (2048 blocks).
__global__ __launch_bounds__(256, 3)
void gemm_qkv_pack(const half_t* __restrict__ x16, const half_t* __restrict__ Wt,
                   float* __restrict__ Part, int kslice, int gemmBlocks,
                   const float* __restrict__ wo, half_t* __restrict__ WtO) {
    __shared__ __align__(16) char lds[49152];
    const int bx = blockIdx.x;
    if (bx < gemmBlocks) {
        const int nb = bx % 48, mb = (bx / 48) & 3, zi = bx / 192;
        const int m0 = mb * 128, n0 = nb * 128;
        f32x4 acc[4][4] = {};
        gemm128_bk32(x16, Wt, NQKV, m0, n0, zi * kslice, kslice / 32, lds, acc);
        const int tid = threadIdx.x;
        const int lane = tid & 63;
        const int quad = lane >> 4, l16 = lane & 15;
        const int w = tid >> 6;
        const int wm = (w & 1) * 64, wn = (w >> 1) * 64;
        float* Cp = Part + (size_t)zi * ((size_t)M_ * NQKV);
#pragma unroll
        for (int i = 0; i < 4; ++i)
#pragma unroll
            for (int j = 0; j < 4; ++j) {
                int col = n0 + wn + j * 16 + l16;
                int rowb = m0 + wm + i * 16 + quad * 4;
#pragma unroll
                for (int rg = 0; rg < 4; ++rg)
                    Cp[(size_t)(rowb + rg) * NQKV + col] = acc[i][j][rg];
            }
    } else {
        int t = bx - gemmBlocks;
        transpose_tile(wo, 4096, (t & 31) * 128, (t & 31) * 128, (t >> 5) * 64,
                       4096, WtO, lds);
    }
}

// ---------------------------------------------------------------------------
// sum_z Part + bias + RoPE -> fp16 q16 [M][4096], k16 [M][1024],
// vt16 [B][KV][HD][S]. Grid (12, 512).
__global__ void qkv_reduce_rope(const float* __restrict__ Part, int nz,
                                const float* __restrict__ bq, const float* __restrict__ bk,
                                const float* __restrict__ bv,
                                const float* __restrict__ fc, const float* __restrict__ fs,
                                half_t* __restrict__ q16, half_t* __restrict__ k16,
                                half_t* __restrict__ vt16) {
    const int row = blockIdx.y;          // b*128 + i
    const int col = (blockIdx.x * 256 + threadIdx.x) * 2;
    const size_t off = (size_t)row * NQKV + col;
    float2 s = *(const float2*)&Part[off];
    for (int z = 1; z < nz; ++z) {
        float2 p = *(const float2*)&Part[(size_t)z * ((size_t)M_ * NQKV) + off];
        s.x += p.x; s.y += p.y;
    }
    float2 bi;
    if (col < 4096)      bi = *(const float2*)&bq[col];
    else if (col < 5120) bi = *(const float2*)&bk[col - 4096];
    else                 bi = *(const float2*)&bv[col - 5120];
    s.x += bi.x; s.y += bi.y;
    if (col < 5120) {    // RoPE (pair-interleaved)
        int d2 = (col >> 1) & 63;
        int i = row & 127;
        float c = fc[i * 64 + d2], sn = fs[i * 64 + d2];
        float re = s.x, im = s.y;
        s.x = re * c - im * sn;
        s.y = re * sn + im * c;
    }
    __align__(4) half_t hh[2] = {(half_t)s.x, (half_t)s.y};
    if (col < 4096) {
        *(unsigned int*)&q16[(size_t)row * 4096 + col] = *(unsigned int*)hh;
    } else if (col < 5120) {
        *(unsigned int*)&k16[(size_t)row * 1024 + (col - 4096)] = *(unsigned int*)hh;
    } else {
        int c = col - 5120;
        int kv = c >> 7, d = c & 127;
        int b = row >> 7, i = row & 127;
        size_t base = ((size_t)(b * 8 + kv) * 128 + d) * 128 + i;
        vt16[base]       = hh[0];
        vt16[base + 128] = hh[1];
    }
}

// ---------------------------------------------------------------------------
// Fused attention: one block per (b, h, 32-row q-chunk). Grid 512.
__global__ __launch_bounds__(256, 2)
void fused_attn(const half_t* __restrict__ q16, const half_t* __restrict__ k16,
                const half_t* __restrict__ vt16, half_t* __restrict__ a16) {
    __shared__ __align__(16) char lds[62464];
    half_t (*Qs)[136] = (half_t(*)[136])lds;            //  8704 B
    half_t (*Ks)[136] = (half_t(*)[136])(lds + 8704);   // 34816 B
    float (*Ps)[132]  = (float(*)[132])(lds + 43520);   // 16896 B
    float (*red)[16]  = (float(*)[16])(lds + 60416);    //  2048 B

    const int tid = threadIdx.x;
    const int qi = blockIdx.x & 3, h = (blockIdx.x >> 2) & 31, b = blockIdx.x >> 7;
    const int kv = h >> 2;
    const int qbase = qi * 32;
    const int lane = tid & 63, w = tid >> 6;
    const int quad = lane >> 4, l16 = lane & 15;
    const int m0 = (w & 1) * 16, half64 = (w >> 1) * 64;

#pragma unroll
    for (int p = 0; p < 2; ++p) {
        int task = tid + p * 256;
        int r = task >> 4, c = task & 15;
        *(uint4*)&Qs[r][c * 8] =
            *(const uint4*)&q16[((size_t)(b * 128 + qbase + r) * 32 + h) * 128 + c * 8];
    }
#pragma unroll
    for (int p = 0; p < 8; ++p) {
        int task = tid + p * 256;
        int r = task >> 4, c = task & 15;
        *(uint4*)&Ks[r][c * 8] =
            *(const uint4*)&k16[((size_t)(b * 128 + r) * 8 + kv) * 128 + c * 8];
    }
    __syncthreads();

    // phase 1: S = Q K^T
    f32x4 s[4] = {};
#pragma unroll
    for (int kc = 0; kc < 4; ++kc) {
        f16x8 af = *(const f16x8*)&Qs[m0 + l16][kc * 32 + quad * 8];
#pragma unroll
        for (int jb = 0; jb < 4; ++jb) {
            f16x8 bf = *(const f16x8*)&Ks[half64 + jb * 16 + l16][kc * 32 + quad * 8];
            s[jb] = __builtin_amdgcn_mfma_f32_16x16x32_f16(af, bf, s[jb], 0, 0, 0);
        }
    }
#pragma unroll
    for (int jb = 0; jb < 4; ++jb) {
        int j = half64 + jb * 16 + l16;
#pragma unroll
        for (int rg = 0; rg < 4; ++rg) {
            int row = m0 + quad * 4 + rg;
            Ps[row][j] = (j <= qbase + row) ? s[jb][rg] * SCALE_ : -1e30f;
        }
    }
    __syncthreads();

    // softmax: thread t -> row r, 16-col segment seg
    const int r = tid >> 3, seg = tid & 7;
    float mx = -1e30f;
#pragma unroll
    for (int i = 0; i < 16; ++i) mx = fmaxf(mx, Ps[r][seg * 16 + i]);
    red[r][seg] = mx;
    __syncthreads();

    uint4 vstage[8];
#pragma unroll
    for (int p = 0; p < 8; ++p) {
        int task = tid + p * 256;
        int rr = task >> 4, c = task & 15;
        vstage[p] = *(const uint4*)&vt16[((size_t)(b * 8 + kv) * 128 + rr) * 128 + c * 8];
    }
    float m = red[r][0];
#pragma unroll
    for (int i = 1; i < 8; ++i) m = fmaxf(m, red[r][i]);
    float sum = 0.f;
#pragma unroll
    for (int i = 0; i < 16; ++i) {
        float e = __expf(Ps[r][seg * 16 + i] - m);
        Ps[r][seg * 16 + i] = e;
        sum += e;
    }
    red[r][8 + seg] = sum;
#pragma unroll
    for (int p = 0; p < 8; ++p) {
        int task = tid + p * 256;
        int rr = task >> 4, c = task & 15;
        *(uint4*)&Ks[rr][c * 8] = vstage[p];   // Vt[d][j]
    }
    __syncthreads();

    float tot = 0.f;
#pragma unroll
    for (int i = 0; i < 8; ++i) tot += red[r][8 + i];
    float inv = 1.0f / tot;
#pragma unroll
    for (int i = 0; i < 16; ++i)
        Qs[r][seg * 16 + i] = (half_t)(Ps[r][seg * 16 + i] * inv);
    __syncthreads();

    // phase 2: O = P V
    f32x4 o[4] = {};
#pragma unroll
    for (int jc = 0; jc < 4; ++jc) {
        f16x8 af = *(const f16x8*)&Qs[m0 + l16][jc * 32 + quad * 8];
#pragma unroll
        for (int db = 0; db < 4; ++db) {
            f16x8 bf = *(const f16x8*)&Ks[half64 + db * 16 + l16][jc * 32 + quad * 8];
            o[db] = __builtin_amdgcn_mfma_f32_16x16x32_f16(af, bf, o[db], 0, 0, 0);
        }
    }
#pragma unroll
    for (int db = 0; db < 4; ++db) {
        int d = half64 + db * 16 + l16;
#pragma unroll
        for (int rg = 0; rg < 4; ++rg) {
            int row = m0 + quad * 4 + rg;
            a16[(size_t)(b * 128 + qbase + row) * 4096 + h * 128 + d] = (half_t)o[db][rg];
        }
    }
}

// ---------------------------------------------------------------------------
// O projection gemm, split-K, 128x128 tiles. Grid 128*z.
__global__ __launch_bounds__(256, 3)
void gemm_o(const half_t* __restrict__ a16, const half_t* __restrict__ WtO,
            float* __restrict__ Part, int kslice) {
    __shared__ __align__(16) char lds[49152];
    const int bx = blockIdx.x;
    const int nb = bx % 32, mb = (bx / 32) & 3, zi = bx / 128;
    const int m0 = mb * 128, n0 = nb * 128;
    f32x4 acc[4][4] = {};
    gemm128_bk32(a16, WtO, 4096, m0, n0, zi * kslice, kslice / 32, lds, acc);
    const int tid = threadIdx.x;
    const int lane = tid & 63;
    const int quad = lane >> 4, l16 = lane & 15;
    const int w = tid >> 6;
    const int wm = (w & 1) * 64, wn = (w >> 1) * 64;
    float* Cp = Part + (size_t)zi * ((size_t)M_ * 4096);
#pragma unroll
    for (int i = 0; i < 4; ++i)
#pragma unroll
        for (int j = 0; j < 4; ++j) {
            int col = n0 + wn + j * 16 + l16;
            int rowb = m0 + wm + i * 16 + quad * 4;
#pragma unroll
            for (int rg = 0; rg < 4; ++rg)
                Cp[(size_t)(rowb + rg) * 4096 + col] = acc[i][j][rg];
        }
}

// ---------------------------------------------------------------------------
// out = sum_z PartO[z] + bo.  One thread per float4. Grid 2048.
__global__ void o_reduce(const float* __restrict__ Part, int nz,
                         const float* __restrict__ bo, float* __restrict__ out) {
    const size_t off = (size_t)(blockIdx.x * 256 + threadIdx.x) * 4;
    float4 s = *(const float4*)&Part[off];
    for (int z = 1; z < nz; ++z) {
        float4 p = *(const float4*)&Part[(size_t)z * ((size_t)M_ * 4096) + off];
        s.x += p.x; s.y += p.y; s.z += p.z; s.w += p.w;
    }
    float4 b = *(const float4*)&bo[off & 4095];
    s.x += b.x; s.y += b.y; s.z += b.z; s.w += b.w;
    *(float4*)&out[off] = s;
}

// ---------------------------------------------------------------------------
extern "C" void kernel_launch(void* const* d_in, const int* in_sizes, int n_in,
                              void* d_out, int out_size, void* d_ws, size_t ws_size,
                              hipStream_t stream) {
    const float* x    = (const float*)d_in[0];
    const float* fc   = (const float*)d_in[2];
    const float* fs   = (const float*)d_in[3];
    const float* wq   = (const float*)d_in[7];
    const float* bq   = (const float*)d_in[8];
    const float* wk   = (const float*)d_in[9];
    const float* bk   = (const float*)d_in[10];
    const float* wv   = (const float*)d_in[11];
    const float* bv   = (const float*)d_in[12];
    const float* wo   = (const float*)d_in[13];
    const float* bo   = (const float*)d_in[14];
    float* out = (float*)d_out;

    half_t* x16  = (half_t*)d_ws;            //  2,097,152 h
    half_t* a16  = x16 + 2097152;            //  2,097,152 h
    half_t* q16  = a16 + 2097152;            //  2,097,152 h
    half_t* k16  = q16 + 2097152;            //    524,288 h
    half_t* vt16 = k16 + 524288;             //    524,288 h
    half_t* Wt   = vt16 + 524288;            // 25,165,824 h (ends @65,011,712 B)
    half_t* WtO  = Wt + 25165824;            // 16,777,216 h (32 MB)
    const size_t fixedA = 65011712 + (size_t)16777216 * 2;   // 98,566,144 B
    float* Part = (float*)((char*)d_ws + fixedA);

    // z=4 needs 50.3 MB of partials beyond fixedA (r0 verified this fits).
    int z = (ws_size >= fixedA + 4 * (size_t)12582912) ? 4 : 2;
    const int kslice = 4096 / z;

    // 1. QKV weight transpose + x convert
    prep_qkv<<<3584, 256, 0, stream>>>(wq, wk, wv, x, Wt, x16);

    // 2. QKV gemm (split-K, counted-vmcnt BK=32 pipeline) + packed wo-T
    gemm_qkv_pack<<<192 * z + 2048, 256, 0, stream>>>(x16, Wt, Part, kslice,
                                                      192 * z, wo, WtO);

    // 3. reduce + bias + rope -> fp16 q/k/vt
    qkv_reduce_rope<<<dim3(12, 512), 256, 0, stream>>>(Part, z, bq, bk, bv,
                                                       fc, fs, q16, k16, vt16);

    // 4. fused attention
    fused_attn<<<512, 256, 0, stream>>>(q16, k16, vt16, a16);

    // 5. O projection (split-K) + reduce
    gemm_o<<<128 * z, 256, 0, stream>>>(a16, WtO, Part, kslice);
    o_reduce<<<2048, 256, 0, stream>>>(Part, z, bo, out);
}